// Round 6
// baseline (4992.035 us; speedup 1.0000x reference)
//
#include <hip/hip_runtime.h>

typedef __attribute__((ext_vector_type(8))) short bf16x8;
typedef __attribute__((ext_vector_type(4))) float f32x4;

__device__ __forceinline__ unsigned short f2bf(float f){
  unsigned u = __float_as_uint(f);
  u += 0x7FFFu + ((u>>16)&1u);
  return (unsigned short)(u>>16);
}
__device__ __forceinline__ void gload16(const void* g, void* l){
  __builtin_amdgcn_global_load_lds(
    (const __attribute__((address_space(1))) unsigned int*)g,
    (__attribute__((address_space(3))) unsigned int*)l, 16, 0, 0);
}

#define OUT_N 8388608

// ---------------- workspace layout (bytes) ----------------
#define WS_ZP   0ULL         // f32 32*34*34*256 = 37,879,808
#define WS_ZF   37879808ULL  // f32 32768*256   = 33,554,432
#define WS_A    71434240ULL  // f32 32768
#define WS_B    71565312ULL  // f32 1024
#define WS_W2T  71569408ULL  // bf16 256*2304   = 1,179,648
#define WS_ZQP  72749056ULL  // bf16 32*34*34*256 = 18,939,904
#define WS_IDX  91688960ULL  // i32 32768
#define WS_PART 91820032ULL  // f32 32768

// ---------------- zero padded borders ----------------
__global__ void k_zero(float* zp, unsigned short* zqp){
  int g = blockIdx.x*256 + threadIdx.x;   // 4224*256 = 32*132*256
  int cell = g>>8, e = g&255;
  int b = cell/132, r2 = cell%132;
  int yy, xx;
  if      (r2<34) { yy=0;        xx=r2;     }
  else if (r2<68) { yy=33;       xx=r2-34;  }
  else if (r2<100){ yy=r2-68+1;  xx=0;      }
  else            { yy=r2-100+1; xx=33;     }
  size_t off = ((size_t)(b*34+yy)*34 + xx)*256 + e;
  zp[off]=0.f; zqp[off]=0;
}

// ---------------- z: NCHW f32 -> padded BHWC f32 ----------------
__global__ void k_pad_z(const float* __restrict__ z, float* __restrict__ zp){
  int bid = blockIdx.x;                 // 1024 = 32 b * 32 y
  int b = bid>>5, y = bid&31;
  __shared__ float tile[64*33];
  int t = threadIdx.x;
  for (int c0=0;c0<256;c0+=64){
    #pragma unroll
    for (int rr=0; rr<8; ++rr){
      int crow = rr*8 + (t>>5);
      int x = t&31;
      tile[crow*33 + x] = z[(((size_t)b*256 + c0 + crow)*32 + y)*32 + x];
    }
    __syncthreads();
    #pragma unroll
    for (int pp=0; pp<8; ++pp){
      int c = t&63, x = pp*4 + (t>>6);
      zp[(((size_t)b*34 + (y+1))*34 + (x+1))*256 + c0 + c] = tile[c*33 + x];
    }
    __syncthreads();
  }
}

// ---------------- unemb_w -> bf16 [o][k], k = tap*256 + e ----------------
__global__ void k_prep_w2(const float* __restrict__ w, unsigned short* __restrict__ out){
  int g = blockIdx.x*256 + threadIdx.x;   // 2304*256 = 589824
  int o = g/2304, k = g - o*2304;
  int tap = k>>8, e = k&255;
  out[g] = f2bf(w[(size_t)o*2304 + e*9 + tap]);
}

// ---------------- conv1: f32, per-output sequential fmaf over k=(c*9+ky*3+kx) ----------------
__global__ __launch_bounds__(256) void k_conv1f(
    const float* __restrict__ zp, const float* __restrict__ w,
    const float* __restrict__ bias, float* __restrict__ zf)
{
  int Mt = blockIdx.x >> 2, Et = blockIdx.x & 3;   // 512 x 4
  int b  = Mt >> 4;
  int y0 = (Mt & 15) * 2;
  int t = threadIdx.x;
  int tm = t >> 4, te = t & 15;
  int yl = tm >> 3, x0 = (tm & 7) * 4;
  __shared__ float patch[4][34][8];   // 4.25 KB
  __shared__ float Wt[64][8][9];      // 18 KB
  float acc[4][4];
  #pragma unroll
  for (int i=0;i<4;i++)
    #pragma unroll
    for (int j=0;j<4;j++) acc[i][j] = 0.f;

  for (int c0 = 0; c0 < 256; c0 += 8){
    __syncthreads();
    for (int l = t; l < 4*34*8; l += 256){
      int rr = l / 272; int rem = l - rr*272;
      int xx = rem >> 3; int cc = rem & 7;
      patch[rr][xx][cc] = zp[((size_t)((b*34 + y0 + rr)*34) + xx)*256 + c0 + cc];
    }
    for (int l = t; l < 64*72; l += 256){
      int e = l / 72; int r = l - e*72;
      Wt[e][r/9][r%9] = w[(size_t)(Et*64 + e)*2304 + c0*9 + r];
    }
    __syncthreads();
    #pragma unroll 2
    for (int cc = 0; cc < 8; ++cc){
      #pragma unroll
      for (int ky = 0; ky < 3; ++ky){
        #pragma unroll
        for (int kx = 0; kx < 3; ++kx){
          float a[4], wv[4];
          #pragma unroll
          for (int i=0;i<4;i++) a[i] = patch[yl + ky][x0 + i + kx][cc];
          #pragma unroll
          for (int j=0;j<4;j++) wv[j] = Wt[te*4 + j][cc][ky*3+kx];
          #pragma unroll
          for (int i=0;i<4;i++)
            #pragma unroll
            for (int j=0;j<4;j++)
              acc[i][j] = fmaf(a[i], wv[j], acc[i][j]);   // k strictly ascending
        }
      }
    }
  }
  #pragma unroll
  for (int j=0;j<4;j++){
    int e = Et*64 + te*4 + j;
    float bv = bias[e];
    #pragma unroll
    for (int i=0;i<4;i++){
      int m = Mt*64 + tm*4 + i;
      zf[(size_t)m*256 + e] = __fadd_rn(acc[i][j], bv);
    }
  }
}

// ---------------- A[m] = numpy-pairwise sum of zf[m][:]^2 ----------------
__device__ __forceinline__ float pairwise128_sq(const float* x){
  float r[8];
  #pragma unroll
  for (int j=0;j<8;j++){ float v = x[j]; r[j] = __fmul_rn(v, v); }
  for (int i=8;i<128;i+=8){
    #pragma unroll
    for (int j=0;j<8;j++){ float v = x[i+j]; r[j] = __fadd_rn(r[j], __fmul_rn(v, v)); }
  }
  float t01 = __fadd_rn(r[0], r[1]), t23 = __fadd_rn(r[2], r[3]);
  float t45 = __fadd_rn(r[4], r[5]), t67 = __fadd_rn(r[6], r[7]);
  return __fadd_rn(__fadd_rn(t01, t23), __fadd_rn(t45, t67));
}

__global__ void k_A(const float* __restrict__ zf, float* __restrict__ A){
  __shared__ float rowbuf[32][256];
  int t = threadIdx.x;
  int m0 = blockIdx.x * 32;     // grid 1024
  for (int l = t; l < 32*256; l += 256){
    int rr = l >> 8, cc = l & 255;
    rowbuf[rr][cc] = zf[(size_t)(m0+rr)*256 + cc];
  }
  __syncthreads();
  if (t < 32){
    float s0 = pairwise128_sq(&rowbuf[t][0]);
    float s1 = pairwise128_sq(&rowbuf[t][128]);
    A[m0+t] = __fadd_rn(s0, s1);
  }
}

__global__ void k_B(const float* __restrict__ cb, float* __restrict__ B){
  int n = blockIdx.x*256 + threadIdx.x;   // grid 4
  __shared__ float rowbuf[256][8];  // unused padding avoidance; small
  (void)rowbuf;
  float loc[256];
  #pragma unroll 8
  for (int e=0;e<256;e++) loc[e] = cb[(size_t)n*256 + e];
  // numpy pairwise on loc
  float r[8];
  #pragma unroll
  for (int j=0;j<8;j++){ float v=loc[j]; r[j]=__fmul_rn(v,v); }
  for (int i=8;i<128;i+=8)
    #pragma unroll
    for (int j=0;j<8;j++){ float v=loc[i+j]; r[j]=__fadd_rn(r[j],__fmul_rn(v,v)); }
  float s0 = __fadd_rn(__fadd_rn(__fadd_rn(r[0],r[1]),__fadd_rn(r[2],r[3])),
                       __fadd_rn(__fadd_rn(r[4],r[5]),__fadd_rn(r[6],r[7])));
  #pragma unroll
  for (int j=0;j<8;j++){ float v=loc[128+j]; r[j]=__fmul_rn(v,v); }
  for (int i=8;i<128;i+=8)
    #pragma unroll
    for (int j=0;j<8;j++){ float v=loc[128+i+j]; r[j]=__fadd_rn(r[j],__fmul_rn(v,v)); }
  float s1 = __fadd_rn(__fadd_rn(__fadd_rn(r[0],r[1]),__fadd_rn(r[2],r[3])),
                       __fadd_rn(__fadd_rn(r[4],r[5]),__fadd_rn(r[6],r[7])));
  B[n] = __fadd_rn(s0, s1);
}

// ---------------- dist: E = seq fmaf dot; d = (A+B) - 2E; argmin first-index ----------------
__global__ __launch_bounds__(256) void k_distf(
    const float* __restrict__ zf, const float* __restrict__ cb,
    const float* __restrict__ A, const float* __restrict__ B,
    int* __restrict__ idxi, float* __restrict__ idxo)
{
  int Mt = blockIdx.x;          // 512
  int t = threadIdx.x, tm = t>>4, tn = t&15;
  __shared__ float zt[64][36];
  __shared__ float ct[64][36];
  float vmin[4]; int imin[4];
  #pragma unroll
  for (int i=0;i<4;i++){ vmin[i]=3.4e38f; imin[i]=0x7fffffff; }
  float Ar[4];
  #pragma unroll
  for (int i=0;i<4;i++) Ar[i] = A[Mt*64 + tm*4 + i];

  for (int nc = 0; nc < 16; ++nc){
    float e[4][4];
    #pragma unroll
    for (int i=0;i<4;i++)
      #pragma unroll
      for (int j=0;j<4;j++) e[i][j] = 0.f;
    for (int d0 = 0; d0 < 256; d0 += 32){
      __syncthreads();
      for (int l = t; l < 64*32; l += 256){
        int rr = l>>5, cc = l&31;
        zt[rr][cc] = zf[(size_t)(Mt*64+rr)*256 + d0 + cc];
        ct[rr][cc] = cb[(size_t)(nc*64+rr)*256 + d0 + cc];
      }
      __syncthreads();
      #pragma unroll
      for (int dd = 0; dd < 32; dd += 4){
        f32x4 av[4], bv[4];
        #pragma unroll
        for (int i=0;i<4;i++) av[i] = *(const f32x4*)&zt[tm*4+i][dd];
        #pragma unroll
        for (int j=0;j<4;j++) bv[j] = *(const f32x4*)&ct[tn*4+j][dd];
        #pragma unroll
        for (int q=0;q<4;q++)
          #pragma unroll
          for (int i=0;i<4;i++)
            #pragma unroll
            for (int j=0;j<4;j++)
              e[i][j] = fmaf(av[i][q], bv[j][q], e[i][j]);   // d ascending
      }
    }
    #pragma unroll
    for (int j=0;j<4;j++){
      int n = nc*64 + tn*4 + j;
      float Bn = B[n];
      #pragma unroll
      for (int i=0;i<4;i++){
        float dv = __fsub_rn(__fadd_rn(Ar[i], Bn), __fmul_rn(2.0f, e[i][j]));
        if (dv < vmin[i]){ vmin[i]=dv; imin[i]=n; }   // strict <, n ascending per thread
      }
    }
  }
  #pragma unroll
  for (int i=0;i<4;i++){
    float v = vmin[i]; int ix = imin[i];
    for (int s=1;s<16;s<<=1){
      float ov = __shfl_xor(v, s, 64);
      int   oi = __shfl_xor(ix, s, 64);
      if (ov < v || (ov==v && oi < ix)){ v=ov; ix=oi; }
    }
    if (tn==0){
      int m = Mt*64 + tm*4 + i;
      idxi[m] = ix;
      idxo[m] = (float)ix;
    }
  }
}

// ---------------- gather z_q -> padded bf16, loss partials ----------------
__global__ void k_gather(const int* __restrict__ idxi, const float* __restrict__ cb,
                         const float* __restrict__ zf,
                         unsigned short* __restrict__ zqp, float* __restrict__ part){
  int m = blockIdx.x, t = threadIdx.x;
  int bi = idxi[m];
  float zq = cb[(size_t)bi*256 + t];
  int b=m>>10, y=(m>>5)&31, x=m&31;
  zqp[(((size_t)b*34 + y+1)*34 + (x+1))*256 + t] = f2bf(zq);
  float d = zq - zf[(size_t)m*256 + t];
  float s = d*d;
  for (int dd=32; dd>0; dd>>=1) s += __shfl_down(s, dd, 64);
  __shared__ float w4[4];
  if ((t&63)==0) w4[t>>6]=s;
  __syncthreads();
  if (t==0) part[m] = w4[0]+w4[1]+w4[2]+w4[3];
}

// ---------------- conv2: bf16 implicit GEMM -> out (NCHW, f32) ----------------
__global__ __launch_bounds__(256, 2) void k_conv2(
    const unsigned short* __restrict__ zqp, const unsigned short* __restrict__ w2t,
    const float* __restrict__ bias, float* __restrict__ out)
{
  __shared__ __align__(16) unsigned short As[128*32], Bs[128*32];
  const int t = threadIdx.x;
  const int Mt = blockIdx.x >> 1, Nt = blockIdx.x & 1;
  const int wid = t>>6, lane = t&63;
  const int wr = wid>>1, wc = wid&1;
  const int q = lane>>4, r = lane&15;

  size_t offA[2], offB[2];
  #pragma unroll
  for (int j=0;j<2;j++){
    int row = j*64 + (t>>2);
    int m = Mt*128 + row;
    int b = m>>10, y=(m>>5)&31, x=m&31;
    offA[j] = ((size_t)((b*34 + y)*34 + x))*512 + (size_t)(t&3)*16;
    offB[j] = (size_t)(Nt*128 + row)*4608 + (size_t)(t&3)*16;
  }
  const unsigned lds0 = wid*1024, lds1 = 4096 + wid*1024;

  f32x4 acc[4][4];
  #pragma unroll
  for (int i=0;i<4;i++)
    #pragma unroll
    for (int j=0;j<4;j++) acc[i][j] = (f32x4){0.f,0.f,0.f,0.f};

  for (int ks=0; ks<72; ++ks){
    int tap = ks>>3;
    int c0b = (ks&7)<<6;
    int dy = tap/3, dx = tap - dy*3;
    size_t tA = (size_t)((dy*34+dx)*512 + c0b);
    size_t tB = (size_t)(tap*512 + c0b);
    __syncthreads();
    gload16((const char*)zqp + offA[0] + tA, (char*)As + lds0);
    gload16((const char*)zqp + offA[1] + tA, (char*)As + lds1);
    gload16((const char*)w2t + offB[0] + tB, (char*)Bs + lds0);
    gload16((const char*)w2t + offB[1] + tB, (char*)Bs + lds1);
    __syncthreads();
    bf16x8 fa[4], fb[4];
    #pragma unroll
    for (int i=0;i<4;i++){
      fa[i] = *(const bf16x8*)&As[(wr*64 + i*16 + r)*32 + q*8];
      fb[i] = *(const bf16x8*)&Bs[(wc*64 + i*16 + r)*32 + q*8];
    }
    #pragma unroll
    for (int i=0;i<4;i++)
      #pragma unroll
      for (int j=0;j<4;j++)
        acc[i][j] = __builtin_amdgcn_mfma_f32_16x16x32_bf16(fa[i], fb[j], acc[i][j], 0,0,0);
  }
  #pragma unroll
  for (int j=0;j<4;j++){
    int o = Nt*128 + wc*64 + j*16 + r;
    float bv = bias[o];
    #pragma unroll
    for (int i=0;i<4;i++){
      int m0 = Mt*128 + wr*64 + i*16 + q*4;
      int b=m0>>10, y=(m0>>5)&31, x=m0&31;
      f32x4 v = acc[i][j];
      v[0]+=bv; v[1]+=bv; v[2]+=bv; v[3]+=bv;
      *(f32x4*)&out[(((size_t)b*256 + o)*32 + y)*32 + x] = v;
    }
  }
}

// ---------------- final loss (f32 at elem OUT_N) ----------------
__global__ void k_loss(const float* __restrict__ part, float* __restrict__ out){
  int t = threadIdx.x;
  float s = 0.f;
  for (int i=t; i<32768; i+=256) s += part[i];
  for (int dd=32; dd>0; dd>>=1) s += __shfl_down(s, dd, 64);
  __shared__ float w4[4];
  if ((t&63)==0) w4[t>>6]=s;
  __syncthreads();
  if (t==0) out[OUT_N] = 1.25f*(w4[0]+w4[1]+w4[2]+w4[3])/8388608.0f;
}

// ---------------- launch ----------------
extern "C" void kernel_launch(void* const* d_in, const int* in_sizes, int n_in,
                              void* d_out, int out_size, void* d_ws, size_t ws_size,
                              hipStream_t stream)
{
  const float* z    = (const float*)d_in[0];
  const float* embw = (const float*)d_in[1];
  const float* embb = (const float*)d_in[2];
  const float* cb   = (const float*)d_in[3];
  const float* unw  = (const float*)d_in[4];
  const float* unb  = (const float*)d_in[5];
  float* out = (float*)d_out;               // f32 output buffer (confirmed R5)
  char* ws = (char*)d_ws;

  float*          zp   = (float*)(ws + WS_ZP);
  float*          zf   = (float*)(ws + WS_ZF);
  float*          Aa   = (float*)(ws + WS_A);
  float*          Bb   = (float*)(ws + WS_B);
  unsigned short* w2t  = (unsigned short*)(ws + WS_W2T);
  unsigned short* zqp  = (unsigned short*)(ws + WS_ZQP);
  int*            idxi = (int*)(ws + WS_IDX);
  float*          part = (float*)(ws + WS_PART);
  float*          idxo = out + OUT_N + 1;

  k_zero   <<<4224, 256, 0, stream>>>(zp, zqp);
  k_pad_z  <<<1024, 256, 0, stream>>>(z, zp);
  k_prep_w2<<<2304, 256, 0, stream>>>(unw, w2t);
  k_conv1f <<<2048, 256, 0, stream>>>(zp, embw, embb, zf);
  k_A      <<<1024, 256, 0, stream>>>(zf, Aa);
  k_B      <<<4,    256, 0, stream>>>(cb, Bb);
  k_distf  <<<512,  256, 0, stream>>>(zf, cb, Aa, Bb, idxi, idxo);
  k_gather <<<32768,256, 0, stream>>>(idxi, cb, zf, zqp, part);
  k_conv2  <<<512,  256, 0, stream>>>(zqp, w2t, unb, out);
  k_loss   <<<1,    256, 0, stream>>>(part, out);
}